// Round 2
// baseline (4950.120 us; speedup 1.0000x reference)
//
#include <hip/hip_runtime.h>
#include <hip/hip_cooperative_groups.h>
#include <stdint.h>

namespace cg = cooperative_groups;

constexpr int SEQL = 128;
constexpr int BAT  = 32;
constexpr int NN   = 1024;   // nodes
constexpr int FIN  = 16;
constexpr int HH   = 256;    // GRU hidden
constexpr int PQ   = SEQL * BAT;   // 4096 (seq*batch pairs)
constexpr float LSM_SHIFT = 6.9314718055994531f;  // ln(1024)

using f32x4 = __attribute__((ext_vector_type(4))) float;
using s16x8 = __attribute__((ext_vector_type(8))) short;

__device__ __forceinline__ unsigned short f2bf(float x) {
  unsigned u = __float_as_uint(x);
  u += 0x7fffu + ((u >> 16) & 1u);
  return (unsigned short)(u >> 16);
}
__device__ __forceinline__ float bf2f(unsigned short b) {
  return __uint_as_float(((unsigned)b) << 16);
}
__device__ __forceinline__ float sigm(float x) { return 1.f / (1.f + __expf(-x)); }

__device__ __forceinline__ void gl_lds16(const void* g, void* l) {
  __builtin_amdgcn_global_load_lds(
      (const __attribute__((address_space(1))) void*)g,
      (__attribute__((address_space(3))) void*)l, 16, 0, 0);
}

// K1: y = x @ gc1_w + gc1_b, written transposed: Yt[(p*2+h)][n], bf16
__global__ __launch_bounds__(256) void k1_xw1(const float* __restrict__ x,
    const float* __restrict__ w1, const float* __restrict__ b1,
    unsigned short* __restrict__ Yt) {
  int idx = blockIdx.x * 256 + threadIdx.x;   // = p*1024 + n
  int p = idx >> 10, n = idx & 1023;
  const float* xp = x + (size_t)idx * FIN;
  float xv[16];
  *(float4*)(xv + 0)  = *(const float4*)(xp + 0);
  *(float4*)(xv + 4)  = *(const float4*)(xp + 4);
  *(float4*)(xv + 8)  = *(const float4*)(xp + 8);
  *(float4*)(xv + 12) = *(const float4*)(xp + 12);
  float y0 = b1[0], y1 = b1[1];
#pragma unroll
  for (int f = 0; f < 16; ++f) { y0 += xv[f] * w1[2*f]; y1 += xv[f] * w1[2*f+1]; }
  Yt[(size_t)(2*p)   * NN + n] = f2bf(y0);
  Yt[(size_t)(2*p+1) * NN + n] = f2bf(y1);
}

// generic fp32 -> bf16 conversion (4 elements / thread)
__global__ __launch_bounds__(256) void k_cvt(const float* __restrict__ in,
    unsigned short* __restrict__ out, int n4) {
  int i = blockIdx.x * 256 + threadIdx.x;
  if (i >= n4) return;
  float4 v = *(const float4*)(in + (size_t)i * 4);
  ushort4 o;
  o.x = f2bf(v.x); o.y = f2bf(v.y); o.z = f2bf(v.z); o.w = f2bf(v.w);
  *(ushort4*)(out + (size_t)i * 4) = o;
}

// biasAdj[j] = bih0[j] - C * sum_k wih0[j][k]   (fp32, one wave per row)
__global__ __launch_bounds__(256) void k_biasadj(const float* __restrict__ wih0,
    const float* __restrict__ bih0, float* __restrict__ biasAdj) {
  int wid = threadIdx.x >> 6, lane = threadIdx.x & 63;
  int j = blockIdx.x * 4 + wid;
  const float* row = wih0 + (size_t)j * 4096;
  float s = 0.f;
  for (int k = lane * 4; k < 4096; k += 256) {
    float4 v = *(const float4*)(row + k);
    s += v.x + v.y + v.z + v.w;
  }
#pragma unroll
  for (int off = 32; off >= 1; off >>= 1) s += __shfl_xor(s, off);
  if (lane == 0) biasAdj[j] = bih0[j] - LSM_SHIFT * s;
}

// MFMA GEMM: C[m][j] = sum_k A[m][k]*B[j][k]; A:(M x K) K-major, B:(N x K) K-major.
// EPI 0: write bf16 transposed C[j][m] with relu; EPI 1: same, no relu;
// EPI 2: write fp32 C[m][j] with per-column bias.
template <int EPI>
__global__ __launch_bounds__(256) void gemm_bt(
    const unsigned short* __restrict__ A, const unsigned short* __restrict__ B,
    void* __restrict__ Cout, const float* __restrict__ bias, int K, int ldc) {
  __shared__ __align__(16) unsigned short As[128 * 64];
  __shared__ __align__(16) unsigned short Bs[128 * 64];
  const int tid = threadIdx.x;
  const int lane = tid & 63, wave = tid >> 6;
  const int ln15 = lane & 15, hi4 = lane >> 4;
  const int wr = wave >> 1, wc = wave & 1;
  const int m0 = blockIdx.y * 128, n0 = blockIdx.x * 128;
  const int rsub = lane >> 3, csub = lane & 7;

  f32x4 acc[4][4];
#pragma unroll
  for (int i = 0; i < 4; ++i)
#pragma unroll
    for (int j = 0; j < 4; ++j) acc[i][j] = {0.f, 0.f, 0.f, 0.f};

  for (int kt = 0; kt < K; kt += 64) {
    __syncthreads();
#pragma unroll
    for (int j = 0; j < 4; ++j) {
      int qq = wave * 4 + j;
      const unsigned short* ga = A + (size_t)(m0 + qq*8 + rsub) * K + kt + csub*8;
      gl_lds16(ga, &As[qq * 512]);
      const unsigned short* gb = B + (size_t)(n0 + qq*8 + rsub) * K + kt + csub*8;
      gl_lds16(gb, &Bs[qq * 512]);
    }
    __syncthreads();
#pragma unroll
    for (int kk = 0; kk < 2; ++kk) {
      s16x8 af[4], bfr[4];
#pragma unroll
      for (int mi = 0; mi < 4; ++mi)
        af[mi] = *(const s16x8*)&As[(wr*64 + mi*16 + ln15) * 64 + kk*32 + hi4*8];
#pragma unroll
      for (int ni = 0; ni < 4; ++ni)
        bfr[ni] = *(const s16x8*)&Bs[(wc*64 + ni*16 + ln15) * 64 + kk*32 + hi4*8];
#pragma unroll
      for (int mi = 0; mi < 4; ++mi)
#pragma unroll
        for (int ni = 0; ni < 4; ++ni)
          acc[mi][ni] = __builtin_amdgcn_mfma_f32_16x16x32_bf16(
              af[mi], bfr[ni], acc[mi][ni], 0, 0, 0);
    }
  }

  if (EPI == 2) {
    float* C = (float*)Cout;
#pragma unroll
    for (int ni = 0; ni < 4; ++ni) {
      int j = n0 + wc*64 + ni*16 + ln15;
      float bv = bias[j];
#pragma unroll
      for (int mi = 0; mi < 4; ++mi) {
        int m = m0 + wr*64 + mi*16 + hi4*4;
#pragma unroll
        for (int r = 0; r < 4; ++r) C[(size_t)(m + r) * ldc + j] = acc[mi][ni][r] + bv;
      }
    }
  } else {
    unsigned short* C = (unsigned short*)Cout;
#pragma unroll
    for (int ni = 0; ni < 4; ++ni) {
      int j = n0 + wc*64 + ni*16 + ln15;
#pragma unroll
      for (int mi = 0; mi < 4; ++mi) {
        int m = m0 + wr*64 + mi*16 + hi4*4;
        ushort4 v;
        float f0 = acc[mi][ni][0], f1 = acc[mi][ni][1], f2 = acc[mi][ni][2], f3 = acc[mi][ni][3];
        if (EPI == 0) { f0 = fmaxf(f0, 0.f); f1 = fmaxf(f1, 0.f); f2 = fmaxf(f2, 0.f); f3 = fmaxf(f3, 0.f); }
        v.x = f2bf(f0); v.y = f2bf(f1); v.z = f2bf(f2); v.w = f2bf(f3);
        *(ushort4*)&C[(size_t)j * ldc + m] = v;
      }
    }
  }
}

__device__ __forceinline__ unsigned k4_proc(unsigned a, unsigned b, float w0, float w1, float bb) {
  float a0 = __uint_as_float(a << 16), a1 = __uint_as_float(a & 0xffff0000u);
  float b0 = __uint_as_float(b << 16), b1 = __uint_as_float(b & 0xffff0000u);
  float y0 = a0 * w0 + b0 * w1 + bb;
  float y1 = a1 * w0 + b1 * w1 + bb;
  return (unsigned)f2bf(y0) | ((unsigned)f2bf(y1) << 16);
}

// K4: Y2t[(p*4+g)][m] = relu'd_z1t[(p*2+0)][m]*W2[0][g] + relu'd_z1t[(p*2+1)][m]*W2[1][g] + b2[g]
__global__ __launch_bounds__(256) void k4_w2(const unsigned short* __restrict__ z1t,
    const float* __restrict__ w2, const float* __restrict__ b2,
    unsigned short* __restrict__ Y2t) {
  int idx = blockIdx.x * 256 + threadIdx.x;   // 16384 * 128 units of 8 elems
  int j4 = idx >> 7, mb = idx & 127;
  int p = j4 >> 2, g = j4 & 3;
  const unsigned short* r0 = z1t + (size_t)(p * 2) * NN + mb * 8;
  const unsigned short* r1 = r0 + NN;
  float w0 = w2[g], w1v = w2[4 + g], bb = b2[g];
  uint4 ua = *(const uint4*)r0;
  uint4 ub = *(const uint4*)r1;
  uint4 o;
  o.x = k4_proc(ua.x, ub.x, w0, w1v, bb);
  o.y = k4_proc(ua.y, ub.y, w0, w1v, bb);
  o.z = k4_proc(ua.z, ub.z, w0, w1v, bb);
  o.w = k4_proc(ua.w, ub.w, w0, w1v, bb);
  *(uint4*)(Y2t + (size_t)j4 * NN + mb * 8) = o;
}

// K6: log_softmax over node axis (contiguous rows of z2t), write GRU input
// Xg[p][m*4+g] bf16, SHIFTED by +ln(1024) to keep values near 0 for bf16.
__global__ __launch_bounds__(256) void k6_lsm(const unsigned short* __restrict__ z2t,
    unsigned short* __restrict__ Xg) {
  int wid = threadIdx.x >> 6, lane = threadIdx.x & 63;
  int r = blockIdx.x * 4 + wid;   // row = p*4+g
  int p = r >> 2, g = r & 3;
  const unsigned short* row = z2t + (size_t)r * NN;
  uint4 u0 = *(const uint4*)(row + lane * 16);
  uint4 u1 = *(const uint4*)(row + lane * 16 + 8);
  unsigned uu[8] = {u0.x, u0.y, u0.z, u0.w, u1.x, u1.y, u1.z, u1.w};
  float v[16];
#pragma unroll
  for (int q = 0; q < 8; ++q) {
    v[2*q]   = __uint_as_float(uu[q] << 16);
    v[2*q+1] = __uint_as_float(uu[q] & 0xffff0000u);
  }
  float mx = v[0];
#pragma unroll
  for (int e = 1; e < 16; ++e) mx = fmaxf(mx, v[e]);
#pragma unroll
  for (int off = 32; off >= 1; off >>= 1) mx = fmaxf(mx, __shfl_xor(mx, off));
  float s = 0.f;
#pragma unroll
  for (int e = 0; e < 16; ++e) s += __expf(v[e] - mx);
#pragma unroll
  for (int off = 32; off >= 1; off >>= 1) s += __shfl_xor(s, off);
  float lse = __logf(s) + mx;
  unsigned short* xr = Xg + (size_t)p * 4096;
#pragma unroll
  for (int e = 0; e < 16; ++e) xr[(lane * 16 + e) * 4 + g] = f2bf(v[e] - lse + LSM_SHIFT);
}

// K8: both GRU layers, pipelined (layer1 one step behind layer0), cooperative.
__global__ __launch_bounds__(256) void k8_gru(
    const float* __restrict__ gi0,
    const float* __restrict__ whh0, const float* __restrict__ bhh0,
    const float* __restrict__ wih1, const float* __restrict__ whh1,
    const float* __restrict__ bih1, const float* __restrict__ bhh1,
    float* __restrict__ out, float* __restrict__ hn,
    float* __restrict__ out0s, float* __restrict__ h1buf) {
  cg::grid_group grid = cg::this_grid();
  const int tid = threadIdx.x, bx = blockIdx.x;
  {
    int gt = bx * 256 + tid;
    if (gt < 8192) out0s[gt] = 0.f;          // h0_{-1} = 0
    else if (gt < 16384) h1buf[gt] = 0.f;    // h1 slot1 = 0 (h1_{-1})
  }
  grid.sync();

  if (bx < 32) {  // ---- layer 0 ----
    const int jj = tid & 7, b = tid >> 3;
    const int j = bx * 8 + jj;
    const float* wr_ = whh0 + (size_t)j * HH;
    const float* wz_ = whh0 + (size_t)(HH + j) * HH;
    const float* wn_ = whh0 + (size_t)(2 * HH + j) * HH;
    const float brr = bhh0[j], bzz = bhh0[HH + j], bnn = bhh0[2 * HH + j];
    for (int t = 0; t < SEQL; ++t) {
      const float* h = out0s + (size_t)t * 8192 + b * HH;
      float ar = brr, az = bzz, an = bnn;
      for (int k = 0; k < HH; k += 4) {
        float4 hv = *(const float4*)(h + k);
        float4 wa = *(const float4*)(wr_ + k);
        float4 wb = *(const float4*)(wz_ + k);
        float4 wc = *(const float4*)(wn_ + k);
        ar += hv.x*wa.x + hv.y*wa.y + hv.z*wa.z + hv.w*wa.w;
        az += hv.x*wb.x + hv.y*wb.y + hv.z*wb.z + hv.w*wb.w;
        an += hv.x*wc.x + hv.y*wc.y + hv.z*wc.z + hv.w*wc.w;
      }
      const float* gi = gi0 + (size_t)(t * BAT + b) * 768;
      float rr = sigm(gi[j] + ar);
      float zz = sigm(gi[HH + j] + az);
      float nn2 = tanhf(gi[2 * HH + j] + rr * an);
      float hnew = (1.f - zz) * nn2 + zz * h[j];
      out0s[(size_t)(t + 1) * 8192 + b * HH + j] = hnew;
      if (t == SEQL - 1) hn[b * HH + j] = hnew;
      grid.sync();
    }
    grid.sync();  // match layer1's trailing phase
  } else {  // ---- layer 1 ----
    const int lb = bx - 32;
    const int role = tid >> 7;     // 0: gi (input) dots, 1: gh (hidden) dots
    const int pr = tid & 127;
    const int jj = pr & 3, b = pr >> 2;
    const int j = lb * 4 + jj;
    __shared__ float sr[128], szz[128], snn[128];
    const float* wsrc = role ? whh1 : wih1;
    const float* w0 = wsrc + (size_t)j * HH;
    const float* w1 = wsrc + (size_t)(HH + j) * HH;
    const float* w2_ = wsrc + (size_t)(2 * HH + j) * HH;
    const float b0 = role ? bhh1[j] : bih1[j];
    const float b1v = role ? bhh1[HH + j] : bih1[HH + j];
    const float b2v = role ? bhh1[2 * HH + j] : bih1[2 * HH + j];
    grid.sync();  // idle during layer0's t=0 phase
    for (int u = 0; u < SEQL; ++u) {
      const float* src = role ? (h1buf + (size_t)((u + 1) & 1) * 8192 + b * HH)
                              : (out0s + (size_t)(u + 1) * 8192 + b * HH);
      float a0 = b0, a1 = b1v, a2 = b2v;
      for (int k = 0; k < HH; k += 4) {
        float4 xv = *(const float4*)(src + k);
        float4 wa = *(const float4*)(w0 + k);
        float4 wb = *(const float4*)(w1 + k);
        float4 wc = *(const float4*)(w2_ + k);
        a0 += xv.x*wa.x + xv.y*wa.y + xv.z*wa.z + xv.w*wa.w;
        a1 += xv.x*wb.x + xv.y*wb.y + xv.z*wb.z + xv.w*wb.w;
        a2 += xv.x*wc.x + xv.y*wc.y + xv.z*wc.z + xv.w*wc.w;
      }
      if (role) { sr[pr] = a0; szz[pr] = a1; snn[pr] = a2; }
      __syncthreads();
      if (!role) {
        float rr = sigm(a0 + sr[pr]);
        float zz = sigm(a1 + szz[pr]);
        float nn2 = tanhf(a2 + rr * snn[pr]);
        float hprev = h1buf[((u + 1) & 1) * 8192 + b * HH + j];
        float hnew = (1.f - zz) * nn2 + zz * hprev;
        h1buf[(u & 1) * 8192 + b * HH + j] = hnew;
        out[(size_t)u * 8192 + b * HH + j] = hnew;
        if (u == SEQL - 1) hn[8192 + b * HH + j] = hnew;
      }
      __syncthreads();
      grid.sync();
    }
  }
}

extern "C" void kernel_launch(void* const* d_in, const int* in_sizes, int n_in,
                              void* d_out, int out_size, void* d_ws, size_t ws_size,
                              hipStream_t stream) {
  const float* x    = (const float*)d_in[0];
  const float* adj  = (const float*)d_in[1];
  const float* gc1w = (const float*)d_in[2];
  const float* gc1b = (const float*)d_in[3];
  const float* gc2w = (const float*)d_in[4];
  const float* gc2b = (const float*)d_in[5];
  const float* wih0 = (const float*)d_in[6];
  const float* whh0 = (const float*)d_in[7];
  const float* bih0 = (const float*)d_in[8];
  const float* bhh0 = (const float*)d_in[9];
  const float* wih1 = (const float*)d_in[10];
  const float* whh1 = (const float*)d_in[11];
  const float* bih1 = (const float*)d_in[12];
  const float* bhh1 = (const float*)d_in[13];

  char* ws = (char*)d_ws;
  const size_t MB = 1048576;
  unsigned short* adjb  = (unsigned short*)(ws + 0);
  unsigned short* Yt    = (unsigned short*)(ws + 2 * MB);
  unsigned short* z1t   = (unsigned short*)(ws + 18 * MB);
  unsigned short* Y2t   = (unsigned short*)(ws + 34 * MB);
  unsigned short* z2t   = (unsigned short*)(ws + 2 * MB);
  unsigned short* Xg    = (unsigned short*)(ws + 34 * MB);
  unsigned short* wih0b = (unsigned short*)(ws + 2 * MB);
  float* biasAdj = (float*)(ws + 8 * MB + 262144);
  float* gi0   = (float*)(ws + 10 * MB);
  float* out0s = (float*)(ws + 23 * MB);
  float* h1buf = (float*)(ws + 28 * MB);
  float* out = (float*)d_out;
  float* hn  = out + (size_t)SEQL * BAT * HH;

  // GCN stage
  k1_xw1<<<PQ * NN / 256, 256, 0, stream>>>(x, gc1w, gc1b, Yt);
  k_cvt<<<(NN * NN / 4 + 255) / 256, 256, 0, stream>>>(adj, adjb, NN * NN / 4);
  gemm_bt<0><<<dim3(64, 8), 256, 0, stream>>>(adjb, Yt, (void*)z1t, nullptr, 1024, 1024);
  k4_w2<<<16384 * 128 / 256, 256, 0, stream>>>(z1t, gc2w, gc2b, Y2t);
  gemm_bt<1><<<dim3(128, 8), 256, 0, stream>>>(adjb, Y2t, (void*)z2t, nullptr, 1024, 1024);
  k6_lsm<<<16384 / 4, 256, 0, stream>>>(z2t, Xg);
  // GRU input GEMM (all timesteps at once), with exact fp32 shift-correction bias
  k_biasadj<<<192, 256, 0, stream>>>(wih0, bih0, biasAdj);
  k_cvt<<<(768 * 4096 / 4 + 255) / 256, 256, 0, stream>>>(wih0, wih0b, 768 * 4096 / 4);
  gemm_bt<2><<<dim3(6, 32), 256, 0, stream>>>(Xg, wih0b, (void*)gi0, biasAdj, 4096, 768);
  // Recurrence (cooperative, 129 pipelined phases)
  void* kargs[] = {(void*)&gi0, (void*)&whh0, (void*)&bhh0, (void*)&wih1, (void*)&whh1,
                   (void*)&bih1, (void*)&bhh1, (void*)&out, (void*)&hn,
                   (void*)&out0s, (void*)&h1buf};
  hipLaunchCooperativeKernel((void*)k8_gru, dim3(96), dim3(256), kargs, 0, stream);
}

// Round 3
// 884.593 us; speedup vs baseline: 5.5959x; 5.5959x over previous
//
#include <hip/hip_runtime.h>
#include <stdint.h>

constexpr int SEQL = 128;
constexpr int BAT  = 32;
constexpr int NN   = 1024;   // nodes
constexpr int FIN  = 16;
constexpr int HH   = 256;    // GRU hidden
constexpr int PQ   = SEQL * BAT;   // 4096 (seq*batch pairs)
constexpr float LSM_SHIFT = 6.9314718055994531f;  // ln(1024)

using f32x4 = __attribute__((ext_vector_type(4))) float;
using s16x8 = __attribute__((ext_vector_type(8))) short;

__device__ __forceinline__ unsigned short f2bf(float x) {
  unsigned u = __float_as_uint(x);
  u += 0x7fffu + ((u >> 16) & 1u);
  return (unsigned short)(u >> 16);
}
__device__ __forceinline__ float sigm(float x) { return 1.f / (1.f + __expf(-x)); }

__device__ __forceinline__ void gl_lds16(const void* g, void* l) {
  __builtin_amdgcn_global_load_lds(
      (const __attribute__((address_space(1))) void*)g,
      (__attribute__((address_space(3))) void*)l, 16, 0, 0);
}

// packed bf16-pair dot product: acc += w.lo*h.lo + w.hi*h.hi
#if __has_builtin(__builtin_amdgcn_fdot2_f32_bf16)
typedef __bf16 bf16x2_t __attribute__((ext_vector_type(2)));
__device__ __forceinline__ float dot2bf(unsigned w, unsigned h, float acc) {
  return __builtin_amdgcn_fdot2_f32_bf16(__builtin_bit_cast(bf16x2_t, w),
                                         __builtin_bit_cast(bf16x2_t, h), acc, false);
}
#else
__device__ __forceinline__ float dot2bf(unsigned w, unsigned h, float acc) {
  acc += __uint_as_float(w << 16) * __uint_as_float(h << 16);
  acc += __uint_as_float(w & 0xffff0000u) * __uint_as_float(h & 0xffff0000u);
  return acc;
}
#endif

// K1: y = x @ gc1_w + gc1_b, written transposed: Yt[(p*2+h)][n], bf16
__global__ __launch_bounds__(256) void k1_xw1(const float* __restrict__ x,
    const float* __restrict__ w1, const float* __restrict__ b1,
    unsigned short* __restrict__ Yt) {
  int idx = blockIdx.x * 256 + threadIdx.x;   // = p*1024 + n
  int p = idx >> 10, n = idx & 1023;
  const float* xp = x + (size_t)idx * FIN;
  float xv[16];
  *(float4*)(xv + 0)  = *(const float4*)(xp + 0);
  *(float4*)(xv + 4)  = *(const float4*)(xp + 4);
  *(float4*)(xv + 8)  = *(const float4*)(xp + 8);
  *(float4*)(xv + 12) = *(const float4*)(xp + 12);
  float y0 = b1[0], y1 = b1[1];
#pragma unroll
  for (int f = 0; f < 16; ++f) { y0 += xv[f] * w1[2*f]; y1 += xv[f] * w1[2*f+1]; }
  Yt[(size_t)(2*p)   * NN + n] = f2bf(y0);
  Yt[(size_t)(2*p+1) * NN + n] = f2bf(y1);
}

// generic fp32 -> bf16 conversion (4 elements / thread)
__global__ __launch_bounds__(256) void k_cvt(const float* __restrict__ in,
    unsigned short* __restrict__ out, int n4) {
  int i = blockIdx.x * 256 + threadIdx.x;
  if (i >= n4) return;
  float4 v = *(const float4*)(in + (size_t)i * 4);
  ushort4 o;
  o.x = f2bf(v.x); o.y = f2bf(v.y); o.z = f2bf(v.z); o.w = f2bf(v.w);
  *(ushort4*)(out + (size_t)i * 4) = o;
}

// biasAdj[j] = bih0[j] - C * sum_k wih0[j][k]   (fp32, one wave per row)
__global__ __launch_bounds__(256) void k_biasadj(const float* __restrict__ wih0,
    const float* __restrict__ bih0, float* __restrict__ biasAdj) {
  int wid = threadIdx.x >> 6, lane = threadIdx.x & 63;
  int j = blockIdx.x * 4 + wid;
  const float* row = wih0 + (size_t)j * 4096;
  float s = 0.f;
  for (int k = lane * 4; k < 4096; k += 256) {
    float4 v = *(const float4*)(row + k);
    s += v.x + v.y + v.z + v.w;
  }
#pragma unroll
  for (int off = 32; off >= 1; off >>= 1) s += __shfl_xor(s, off);
  if (lane == 0) biasAdj[j] = bih0[j] - LSM_SHIFT * s;
}

// Weight prep for the recurrence: W fp32 [768][256] -> gather-layout packed
// k-pair bf16 uints. Element (j, k2): i=j>>8, jg=j&255, kg=k2>>5, c=(k2>>2)&7,
// u=k2&3 -> Wp[(((i*4+kg)*8+c)<<10) + (jg<<2) + u]
__global__ __launch_bounds__(256) void k_prep(const float* __restrict__ W,
    unsigned* __restrict__ Wp) {
  int tid = blockIdx.x * 256 + threadIdx.x;  // 98304
  int j = tid >> 7, k2 = tid & 127;
  float2 wv = *(const float2*)(W + (size_t)j * 256 + 2 * k2);
  unsigned pk = (unsigned)f2bf(wv.x) | ((unsigned)f2bf(wv.y) << 16);
  int i = j >> 8, jg = j & 255, kg = k2 >> 5, c = (k2 >> 2) & 7, u = k2 & 3;
  Wp[((((i * 4 + kg) * 8 + c)) << 10) + (jg << 2) + u] = pk;
}

// MFMA GEMM: C[m][j] = sum_k A[m][k]*B[j][k]; A:(M x K) K-major, B:(N x K) K-major.
// EPI 0: write bf16 transposed C[j][m] with relu; EPI 1: same, no relu;
// EPI 2: write fp32 C[m][j] with per-column bias.
template <int EPI>
__global__ __launch_bounds__(256) void gemm_bt(
    const unsigned short* __restrict__ A, const unsigned short* __restrict__ B,
    void* __restrict__ Cout, const float* __restrict__ bias, int K, int ldc) {
  __shared__ __align__(16) unsigned short As[128 * 64];
  __shared__ __align__(16) unsigned short Bs[128 * 64];
  const int tid = threadIdx.x;
  const int lane = tid & 63, wave = tid >> 6;
  const int ln15 = lane & 15, hi4 = lane >> 4;
  const int wr = wave >> 1, wc = wave & 1;
  const int m0 = blockIdx.y * 128, n0 = blockIdx.x * 128;
  const int rsub = lane >> 3, csub = lane & 7;

  f32x4 acc[4][4];
#pragma unroll
  for (int i = 0; i < 4; ++i)
#pragma unroll
    for (int j = 0; j < 4; ++j) acc[i][j] = {0.f, 0.f, 0.f, 0.f};

  for (int kt = 0; kt < K; kt += 64) {
    __syncthreads();
#pragma unroll
    for (int j = 0; j < 4; ++j) {
      int qq = wave * 4 + j;
      const unsigned short* ga = A + (size_t)(m0 + qq*8 + rsub) * K + kt + csub*8;
      gl_lds16(ga, &As[qq * 512]);
      const unsigned short* gb = B + (size_t)(n0 + qq*8 + rsub) * K + kt + csub*8;
      gl_lds16(gb, &Bs[qq * 512]);
    }
    __syncthreads();
#pragma unroll
    for (int kk = 0; kk < 2; ++kk) {
      s16x8 af[4], bfr[4];
#pragma unroll
      for (int mi = 0; mi < 4; ++mi)
        af[mi] = *(const s16x8*)&As[(wr*64 + mi*16 + ln15) * 64 + kk*32 + hi4*8];
#pragma unroll
      for (int ni = 0; ni < 4; ++ni)
        bfr[ni] = *(const s16x8*)&Bs[(wc*64 + ni*16 + ln15) * 64 + kk*32 + hi4*8];
#pragma unroll
      for (int mi = 0; mi < 4; ++mi)
#pragma unroll
        for (int ni = 0; ni < 4; ++ni)
          acc[mi][ni] = __builtin_amdgcn_mfma_f32_16x16x32_bf16(
              af[mi], bfr[ni], acc[mi][ni], 0, 0, 0);
    }
  }

  if (EPI == 2) {
    float* C = (float*)Cout;
#pragma unroll
    for (int ni = 0; ni < 4; ++ni) {
      int j = n0 + wc*64 + ni*16 + ln15;
      float bv = bias[j];
#pragma unroll
      for (int mi = 0; mi < 4; ++mi) {
        int m = m0 + wr*64 + mi*16 + hi4*4;
#pragma unroll
        for (int r = 0; r < 4; ++r) C[(size_t)(m + r) * ldc + j] = acc[mi][ni][r] + bv;
      }
    }
  } else {
    unsigned short* C = (unsigned short*)Cout;
#pragma unroll
    for (int ni = 0; ni < 4; ++ni) {
      int j = n0 + wc*64 + ni*16 + ln15;
#pragma unroll
      for (int mi = 0; mi < 4; ++mi) {
        int m = m0 + wr*64 + mi*16 + hi4*4;
        ushort4 v;
        float f0 = acc[mi][ni][0], f1 = acc[mi][ni][1], f2 = acc[mi][ni][2], f3 = acc[mi][ni][3];
        if (EPI == 0) { f0 = fmaxf(f0, 0.f); f1 = fmaxf(f1, 0.f); f2 = fmaxf(f2, 0.f); f3 = fmaxf(f3, 0.f); }
        v.x = f2bf(f0); v.y = f2bf(f1); v.z = f2bf(f2); v.w = f2bf(f3);
        *(ushort4*)&C[(size_t)j * ldc + m] = v;
      }
    }
  }
}

__device__ __forceinline__ unsigned k4_proc(unsigned a, unsigned b, float w0, float w1, float bb) {
  float a0 = __uint_as_float(a << 16), a1 = __uint_as_float(a & 0xffff0000u);
  float b0 = __uint_as_float(b << 16), b1 = __uint_as_float(b & 0xffff0000u);
  float y0 = a0 * w0 + b0 * w1 + bb;
  float y1 = a1 * w0 + b1 * w1 + bb;
  return (unsigned)f2bf(y0) | ((unsigned)f2bf(y1) << 16);
}

// K4: Y2t[(p*4+g)][m] = z1t[(p*2+0)][m]*W2[0][g] + z1t[(p*2+1)][m]*W2[1][g] + b2[g]
__global__ __launch_bounds__(256) void k4_w2(const unsigned short* __restrict__ z1t,
    const float* __restrict__ w2, const float* __restrict__ b2,
    unsigned short* __restrict__ Y2t) {
  int idx = blockIdx.x * 256 + threadIdx.x;
  int j4 = idx >> 7, mb = idx & 127;
  int p = j4 >> 2, g = j4 & 3;
  const unsigned short* r0 = z1t + (size_t)(p * 2) * NN + mb * 8;
  const unsigned short* r1 = r0 + NN;
  float w0 = w2[g], w1v = w2[4 + g], bb = b2[g];
  uint4 ua = *(const uint4*)r0;
  uint4 ub = *(const uint4*)r1;
  uint4 o;
  o.x = k4_proc(ua.x, ub.x, w0, w1v, bb);
  o.y = k4_proc(ua.y, ub.y, w0, w1v, bb);
  o.z = k4_proc(ua.z, ub.z, w0, w1v, bb);
  o.w = k4_proc(ua.w, ub.w, w0, w1v, bb);
  *(uint4*)(Y2t + (size_t)j4 * NN + mb * 8) = o;
}

// K6: log_softmax over node axis, write GRU input Xg[p][m*4+g] bf16,
// shifted by +ln(1024) to keep values near 0 for bf16 precision.
__global__ __launch_bounds__(256) void k6_lsm(const unsigned short* __restrict__ z2t,
    unsigned short* __restrict__ Xg) {
  int wid = threadIdx.x >> 6, lane = threadIdx.x & 63;
  int r = blockIdx.x * 4 + wid;   // row = p*4+g
  int p = r >> 2, g = r & 3;
  const unsigned short* row = z2t + (size_t)r * NN;
  uint4 u0 = *(const uint4*)(row + lane * 16);
  uint4 u1 = *(const uint4*)(row + lane * 16 + 8);
  unsigned uu[8] = {u0.x, u0.y, u0.z, u0.w, u1.x, u1.y, u1.z, u1.w};
  float v[16];
#pragma unroll
  for (int q = 0; q < 8; ++q) {
    v[2*q]   = __uint_as_float(uu[q] << 16);
    v[2*q+1] = __uint_as_float(uu[q] & 0xffff0000u);
  }
  float mx = v[0];
#pragma unroll
  for (int e = 1; e < 16; ++e) mx = fmaxf(mx, v[e]);
#pragma unroll
  for (int off = 32; off >= 1; off >>= 1) mx = fmaxf(mx, __shfl_xor(mx, off));
  float s = 0.f;
#pragma unroll
  for (int e = 0; e < 16; ++e) s += __expf(v[e] - mx);
#pragma unroll
  for (int off = 32; off >= 1; off >>= 1) s += __shfl_xor(s, off);
  float lse = __logf(s) + mx;
  unsigned short* xr = Xg + (size_t)p * 4096;
#pragma unroll
  for (int e = 0; e < 16; ++e) xr[(lane * 16 + e) * 4 + g] = f2bf(v[e] - lse + LSM_SHIFT);
}

// Recurrent layer, one block per batch element, NO cross-block sync.
// 1024 threads = (kg 0..3) x (jg 0..255); thread (kg,jg) computes K-slice
// [64kg,64kg+64) partial dots for gates jg, 256+jg, 512+jg. Gate thread jg
// (kg==0) owns h[jg] in a register. Weights streamed from L2 each step in
// the gather layout produced by k_prep. gi includes b_ih (from GEMM bias).
// L==0: writes h0 bf16 (K-major rows for gi1 GEMM). L==1: writes fp32 out.
template <int L>
__global__ __launch_bounds__(1024) void k_rnn(const float* __restrict__ gi,
    const unsigned* __restrict__ Wp, const float* __restrict__ bhh,
    unsigned short* __restrict__ hb_out, float* __restrict__ hf_out,
    float* __restrict__ hn_row) {
  const int b = blockIdx.x, tid = threadIdx.x;
  const int jg = tid & 255, kg = tid >> 8;
  __shared__ __align__(16) unsigned hpk[128];
  __shared__ float part[4][776];
  float hprev = 0.f;
  float br = 0.f, bz = 0.f, bn = 0.f;
  if (tid < 256) { br = bhh[jg]; bz = bhh[256 + jg]; bn = bhh[512 + jg]; }
  if (tid < 128) hpk[tid] = 0u;
  __syncthreads();
  const unsigned* wbase = Wp + (size_t)(kg * 8) * 1024 + jg * 4;
  for (int t = 0; t < SEQL; ++t) {
    unsigned hk[32];
#pragma unroll
    for (int c4 = 0; c4 < 8; ++c4)
      *(uint4*)&hk[c4 * 4] = *(const uint4*)&hpk[kg * 32 + c4 * 4];
    float a[3];
#pragma unroll
    for (int i = 0; i < 3; ++i) {
      const unsigned* wb = wbase + (size_t)i * 32768;  // i*4*8*1024
      float acc = 0.f;
#pragma unroll
      for (int c = 0; c < 8; ++c) {
        uint4 w = *(const uint4*)(wb + c * 1024);
        acc = dot2bf(w.x, hk[c * 4 + 0], acc);
        acc = dot2bf(w.y, hk[c * 4 + 1], acc);
        acc = dot2bf(w.z, hk[c * 4 + 2], acc);
        acc = dot2bf(w.w, hk[c * 4 + 3], acc);
      }
      a[i] = acc;
    }
    part[kg][jg]       = a[0];
    part[kg][256 + jg] = a[1];
    part[kg][512 + jg] = a[2];
    __syncthreads();
    if (tid < 256) {
      const float* gr = gi + (size_t)(t * BAT + b) * 768;
      float ghr = part[0][jg] + part[1][jg] + part[2][jg] + part[3][jg] + br;
      float ghz = part[0][256+jg] + part[1][256+jg] + part[2][256+jg] + part[3][256+jg] + bz;
      float ghn = part[0][512+jg] + part[1][512+jg] + part[2][512+jg] + part[3][512+jg] + bn;
      float r = sigm(gr[jg] + ghr);
      float z = sigm(gr[256 + jg] + ghz);
      float nn = tanhf(gr[512 + jg] + r * ghn);
      float hnew = (1.f - z) * nn + z * hprev;
      hprev = hnew;
      unsigned short hbb = f2bf(hnew);
      if (L == 0) hb_out[(size_t)(t * BAT + b) * 256 + jg] = hbb;
      else        hf_out[(size_t)(t * BAT + b) * 256 + jg] = hnew;
      unsigned lo = (unsigned)hbb;
      unsigned hi = (unsigned)__shfl_down((int)lo, 1);
      if (!(jg & 1)) hpk[jg >> 1] = lo | (hi << 16);
      if (t == SEQL - 1) hn_row[b * 256 + jg] = hnew;
    }
    __syncthreads();
  }
}

extern "C" void kernel_launch(void* const* d_in, const int* in_sizes, int n_in,
                              void* d_out, int out_size, void* d_ws, size_t ws_size,
                              hipStream_t stream) {
  const float* x    = (const float*)d_in[0];
  const float* adj  = (const float*)d_in[1];
  const float* gc1w = (const float*)d_in[2];
  const float* gc1b = (const float*)d_in[3];
  const float* gc2w = (const float*)d_in[4];
  const float* gc2b = (const float*)d_in[5];
  const float* wih0 = (const float*)d_in[6];
  const float* whh0 = (const float*)d_in[7];
  const float* bih0 = (const float*)d_in[8];
  const float* bhh0 = (const float*)d_in[9];
  const float* wih1 = (const float*)d_in[10];
  const float* whh1 = (const float*)d_in[11];
  const float* bih1 = (const float*)d_in[12];
  const float* bhh1 = (const float*)d_in[13];

  char* ws = (char*)d_ws;
  const size_t MB = 1048576;
  // lifetimes: Yt[2,18) K1..G2a; z1t[18,34) G2a..K4; Y2t[34,66) K4..G2b;
  // z2t[2,34) G2b..K6; Xg[34,66) K6..G3; wih0b[2,9) after K6; gi0[10,23);
  // Whh0p[23,24); Whh1p[24,25); wih1b[25,25.5); h0b[25.5,27.5);
  // gi1[28,41) (over dead Xg). Peak 66 MB.
  unsigned short* adjb  = (unsigned short*)(ws + 0);
  unsigned short* Yt    = (unsigned short*)(ws + 2 * MB);
  unsigned short* z1t   = (unsigned short*)(ws + 18 * MB);
  unsigned short* Y2t   = (unsigned short*)(ws + 34 * MB);
  unsigned short* z2t   = (unsigned short*)(ws + 2 * MB);
  unsigned short* Xg    = (unsigned short*)(ws + 34 * MB);
  unsigned short* wih0b = (unsigned short*)(ws + 2 * MB);
  float* biasAdj        = (float*)(ws + 9 * MB);
  float* gi0            = (float*)(ws + 10 * MB);
  unsigned* Whh0p       = (unsigned*)(ws + 23 * MB);
  unsigned* Whh1p       = (unsigned*)(ws + 24 * MB);
  unsigned short* wih1b = (unsigned short*)(ws + 25 * MB);
  unsigned short* h0b   = (unsigned short*)(ws + 25 * MB + 512 * 1024);
  float* gi1            = (float*)(ws + 28 * MB);
  float* out = (float*)d_out;
  float* hn  = out + (size_t)SEQL * BAT * HH;

  // GCN stage
  k1_xw1<<<PQ * NN / 256, 256, 0, stream>>>(x, gc1w, gc1b, Yt);
  k_cvt<<<(NN * NN / 4 + 255) / 256, 256, 0, stream>>>(adj, adjb, NN * NN / 4);
  gemm_bt<0><<<dim3(64, 8), 256, 0, stream>>>(adjb, Yt, (void*)z1t, nullptr, 1024, 1024);
  k4_w2<<<16384 * 128 / 256, 256, 0, stream>>>(z1t, gc2w, gc2b, Y2t);
  gemm_bt<1><<<dim3(128, 8), 256, 0, stream>>>(adjb, Y2t, (void*)z2t, nullptr, 1024, 1024);
  k6_lsm<<<16384 / 4, 256, 0, stream>>>(z2t, Xg);
  // GRU layer-0 input GEMM (all timesteps), exact fp32 shift-correction bias
  k_biasadj<<<192, 256, 0, stream>>>(wih0, bih0, biasAdj);
  k_cvt<<<(768 * 4096 / 4 + 255) / 256, 256, 0, stream>>>(wih0, wih0b, 768 * 4096 / 4);
  gemm_bt<2><<<dim3(6, 32), 256, 0, stream>>>(Xg, wih0b, (void*)gi0, biasAdj, 4096, 768);
  // Recurrence weight prep
  k_prep<<<384, 256, 0, stream>>>(whh0, Whh0p);
  k_prep<<<384, 256, 0, stream>>>(whh1, Whh1p);
  k_cvt<<<(768 * 256 / 4 + 255) / 256, 256, 0, stream>>>(wih1, wih1b, 768 * 256 / 4);
  // Layer 0 recurrence (32 independent chains, no grid sync)
  k_rnn<0><<<32, 1024, 0, stream>>>(gi0, Whh0p, bhh0, h0b, nullptr, hn);
  // Layer 1 input GEMM: gi1 = H0 @ wih1^T + bih1
  gemm_bt<2><<<dim3(6, 32), 256, 0, stream>>>(h0b, wih1b, (void*)gi1, bih1, 256, 768);
  // Layer 1 recurrence -> writes final out + hn[1]
  k_rnn<1><<<32, 1024, 0, stream>>>(gi1, Whh1p, bhh1, nullptr, out, hn + BAT * HH);
}

// Round 4
// 659.681 us; speedup vs baseline: 7.5038x; 1.3409x over previous
//
#include <hip/hip_runtime.h>
#include <stdint.h>

constexpr int SEQL = 128;
constexpr int BAT  = 32;
constexpr int NN   = 1024;   // nodes
constexpr int FIN  = 16;
constexpr int HH   = 256;    // GRU hidden
constexpr int PQ   = SEQL * BAT;   // 4096 (seq*batch pairs)
constexpr float LSM_SHIFT = 6.9314718055994531f;  // ln(1024)

using f32x4 = __attribute__((ext_vector_type(4))) float;
using s16x8 = __attribute__((ext_vector_type(8))) short;

__device__ __forceinline__ unsigned short f2bf(float x) {
  unsigned u = __float_as_uint(x);
  u += 0x7fffu + ((u >> 16) & 1u);
  return (unsigned short)(u >> 16);
}
__device__ __forceinline__ float sigm(float x) { return 1.f / (1.f + __expf(-x)); }

__device__ __forceinline__ void gl_lds16(const void* g, void* l) {
  __builtin_amdgcn_global_load_lds(
      (const __attribute__((address_space(1))) void*)g,
      (__attribute__((address_space(3))) void*)l, 16, 0, 0);
}

// packed bf16-pair dot product: acc += w.lo*h.lo + w.hi*h.hi
#if __has_builtin(__builtin_amdgcn_fdot2_f32_bf16)
typedef __bf16 bf16x2_t __attribute__((ext_vector_type(2)));
__device__ __forceinline__ float dot2bf(unsigned w, unsigned h, float acc) {
  return __builtin_amdgcn_fdot2_f32_bf16(__builtin_bit_cast(bf16x2_t, w),
                                         __builtin_bit_cast(bf16x2_t, h), acc, false);
}
#else
__device__ __forceinline__ float dot2bf(unsigned w, unsigned h, float acc) {
  acc += __uint_as_float(w << 16) * __uint_as_float(h << 16);
  acc += __uint_as_float(w & 0xffff0000u) * __uint_as_float(h & 0xffff0000u);
  return acc;
}
#endif

// K1: y = x @ gc1_w + gc1_b, written transposed: Yt[(p*2+h)][n], bf16
__global__ __launch_bounds__(256) void k1_xw1(const float* __restrict__ x,
    const float* __restrict__ w1, const float* __restrict__ b1,
    unsigned short* __restrict__ Yt) {
  int idx = blockIdx.x * 256 + threadIdx.x;   // = p*1024 + n
  int p = idx >> 10, n = idx & 1023;
  const float* xp = x + (size_t)idx * FIN;
  float xv[16];
  *(float4*)(xv + 0)  = *(const float4*)(xp + 0);
  *(float4*)(xv + 4)  = *(const float4*)(xp + 4);
  *(float4*)(xv + 8)  = *(const float4*)(xp + 8);
  *(float4*)(xv + 12) = *(const float4*)(xp + 12);
  float y0 = b1[0], y1 = b1[1];
#pragma unroll
  for (int f = 0; f < 16; ++f) { y0 += xv[f] * w1[2*f]; y1 += xv[f] * w1[2*f+1]; }
  Yt[(size_t)(2*p)   * NN + n] = f2bf(y0);
  Yt[(size_t)(2*p+1) * NN + n] = f2bf(y1);
}

// generic fp32 -> bf16 conversion (4 elements / thread)
__global__ __launch_bounds__(256) void k_cvt(const float* __restrict__ in,
    unsigned short* __restrict__ out, int n4) {
  int i = blockIdx.x * 256 + threadIdx.x;
  if (i >= n4) return;
  float4 v = *(const float4*)(in + (size_t)i * 4);
  ushort4 o;
  o.x = f2bf(v.x); o.y = f2bf(v.y); o.z = f2bf(v.z); o.w = f2bf(v.w);
  *(ushort4*)(out + (size_t)i * 4) = o;
}

// biasAdj[j] = bih0[j] - C * sum_k wih0[j][k]   (fp32, one wave per row)
__global__ __launch_bounds__(256) void k_biasadj(const float* __restrict__ wih0,
    const float* __restrict__ bih0, float* __restrict__ biasAdj) {
  int wid = threadIdx.x >> 6, lane = threadIdx.x & 63;
  int j = blockIdx.x * 4 + wid;
  const float* row = wih0 + (size_t)j * 4096;
  float s = 0.f;
  for (int k = lane * 4; k < 4096; k += 256) {
    float4 v = *(const float4*)(row + k);
    s += v.x + v.y + v.z + v.w;
  }
#pragma unroll
  for (int off = 32; off >= 1; off >>= 1) s += __shfl_xor(s, off);
  if (lane == 0) biasAdj[j] = bih0[j] - LSM_SHIFT * s;
}

// Weight prep for the register-resident recurrence.
// W fp32 [768][256] -> packed k-pair bf16 uints in gather layout:
// element (j,k2): i=j>>8, jg=j&255, kg=k2>>6, c=(k2>>2)&15, u=k2&3
//   -> Wp[(((i*2+kg)*16+c)<<10) + (jg<<2) + u]
// so thread (kg,jg) loads gate i chunk c as a contiguous uint4, and a wave's
// 64 consecutive jg lanes cover 1KB contiguous.
__global__ __launch_bounds__(256) void k_prep(const float* __restrict__ W,
    unsigned* __restrict__ Wp) {
  int tid = blockIdx.x * 256 + threadIdx.x;  // 98304
  int j = tid >> 7, k2 = tid & 127;
  float2 wv = *(const float2*)(W + (size_t)j * 256 + 2 * k2);
  unsigned pk = (unsigned)f2bf(wv.x) | ((unsigned)f2bf(wv.y) << 16);
  int i = j >> 8, jg = j & 255, kg = k2 >> 6, c = (k2 >> 2) & 15, u = k2 & 3;
  Wp[(((i * 2 + kg) * 16 + c) << 10) + (jg << 2) + u] = pk;
}

// MFMA GEMM: C[m][j] = sum_k A[m][k]*B[j][k]; A:(M x K) K-major, B:(N x K) K-major.
// EPI 0: write bf16 transposed C[j][m] with relu; EPI 1: same, no relu;
// EPI 2: write fp32 C[m][j] with per-column bias.
template <int EPI>
__global__ __launch_bounds__(256) void gemm_bt(
    const unsigned short* __restrict__ A, const unsigned short* __restrict__ B,
    void* __restrict__ Cout, const float* __restrict__ bias, int K, int ldc) {
  __shared__ __align__(16) unsigned short As[128 * 64];
  __shared__ __align__(16) unsigned short Bs[128 * 64];
  const int tid = threadIdx.x;
  const int lane = tid & 63, wave = tid >> 6;
  const int ln15 = lane & 15, hi4 = lane >> 4;
  const int wr = wave >> 1, wc = wave & 1;
  const int m0 = blockIdx.y * 128, n0 = blockIdx.x * 128;
  const int rsub = lane >> 3, csub = lane & 7;

  f32x4 acc[4][4];
#pragma unroll
  for (int i = 0; i < 4; ++i)
#pragma unroll
    for (int j = 0; j < 4; ++j) acc[i][j] = {0.f, 0.f, 0.f, 0.f};

  for (int kt = 0; kt < K; kt += 64) {
    __syncthreads();
#pragma unroll
    for (int j = 0; j < 4; ++j) {
      int qq = wave * 4 + j;
      const unsigned short* ga = A + (size_t)(m0 + qq*8 + rsub) * K + kt + csub*8;
      gl_lds16(ga, &As[qq * 512]);
      const unsigned short* gb = B + (size_t)(n0 + qq*8 + rsub) * K + kt + csub*8;
      gl_lds16(gb, &Bs[qq * 512]);
    }
    __syncthreads();
#pragma unroll
    for (int kk = 0; kk < 2; ++kk) {
      s16x8 af[4], bfr[4];
#pragma unroll
      for (int mi = 0; mi < 4; ++mi)
        af[mi] = *(const s16x8*)&As[(wr*64 + mi*16 + ln15) * 64 + kk*32 + hi4*8];
#pragma unroll
      for (int ni = 0; ni < 4; ++ni)
        bfr[ni] = *(const s16x8*)&Bs[(wc*64 + ni*16 + ln15) * 64 + kk*32 + hi4*8];
#pragma unroll
      for (int mi = 0; mi < 4; ++mi)
#pragma unroll
        for (int ni = 0; ni < 4; ++ni)
          acc[mi][ni] = __builtin_amdgcn_mfma_f32_16x16x32_bf16(
              af[mi], bfr[ni], acc[mi][ni], 0, 0, 0);
    }
  }

  if (EPI == 2) {
    float* C = (float*)Cout;
#pragma unroll
    for (int ni = 0; ni < 4; ++ni) {
      int j = n0 + wc*64 + ni*16 + ln15;
      float bv = bias[j];
#pragma unroll
      for (int mi = 0; mi < 4; ++mi) {
        int m = m0 + wr*64 + mi*16 + hi4*4;
#pragma unroll
        for (int r = 0; r < 4; ++r) C[(size_t)(m + r) * ldc + j] = acc[mi][ni][r] + bv;
      }
    }
  } else {
    unsigned short* C = (unsigned short*)Cout;
#pragma unroll
    for (int ni = 0; ni < 4; ++ni) {
      int j = n0 + wc*64 + ni*16 + ln15;
#pragma unroll
      for (int mi = 0; mi < 4; ++mi) {
        int m = m0 + wr*64 + mi*16 + hi4*4;
        ushort4 v;
        float f0 = acc[mi][ni][0], f1 = acc[mi][ni][1], f2 = acc[mi][ni][2], f3 = acc[mi][ni][3];
        if (EPI == 0) { f0 = fmaxf(f0, 0.f); f1 = fmaxf(f1, 0.f); f2 = fmaxf(f2, 0.f); f3 = fmaxf(f3, 0.f); }
        v.x = f2bf(f0); v.y = f2bf(f1); v.z = f2bf(f2); v.w = f2bf(f3);
        *(ushort4*)&C[(size_t)j * ldc + m] = v;
      }
    }
  }
}

__device__ __forceinline__ unsigned k4_proc(unsigned a, unsigned b, float w0, float w1, float bb) {
  float a0 = __uint_as_float(a << 16), a1 = __uint_as_float(a & 0xffff0000u);
  float b0 = __uint_as_float(b << 16), b1 = __uint_as_float(b & 0xffff0000u);
  float y0 = a0 * w0 + b0 * w1 + bb;
  float y1 = a1 * w0 + b1 * w1 + bb;
  return (unsigned)f2bf(y0) | ((unsigned)f2bf(y1) << 16);
}

// K4: Y2t[(p*4+g)][m] = z1t[(p*2+0)][m]*W2[0][g] + z1t[(p*2+1)][m]*W2[1][g] + b2[g]
__global__ __launch_bounds__(256) void k4_w2(const unsigned short* __restrict__ z1t,
    const float* __restrict__ w2, const float* __restrict__ b2,
    unsigned short* __restrict__ Y2t) {
  int idx = blockIdx.x * 256 + threadIdx.x;
  int j4 = idx >> 7, mb = idx & 127;
  int p = j4 >> 2, g = j4 & 3;
  const unsigned short* r0 = z1t + (size_t)(p * 2) * NN + mb * 8;
  const unsigned short* r1 = r0 + NN;
  float w0 = w2[g], w1v = w2[4 + g], bb = b2[g];
  uint4 ua = *(const uint4*)r0;
  uint4 ub = *(const uint4*)r1;
  uint4 o;
  o.x = k4_proc(ua.x, ub.x, w0, w1v, bb);
  o.y = k4_proc(ua.y, ub.y, w0, w1v, bb);
  o.z = k4_proc(ua.z, ub.z, w0, w1v, bb);
  o.w = k4_proc(ua.w, ub.w, w0, w1v, bb);
  *(uint4*)(Y2t + (size_t)j4 * NN + mb * 8) = o;
}

// K6: log_softmax over node axis, write GRU input Xg[p][m*4+g] bf16,
// shifted by +ln(1024) to keep values near 0 for bf16 precision.
__global__ __launch_bounds__(256) void k6_lsm(const unsigned short* __restrict__ z2t,
    unsigned short* __restrict__ Xg) {
  int wid = threadIdx.x >> 6, lane = threadIdx.x & 63;
  int r = blockIdx.x * 4 + wid;   // row = p*4+g
  int p = r >> 2, g = r & 3;
  const unsigned short* row = z2t + (size_t)r * NN;
  uint4 u0 = *(const uint4*)(row + lane * 16);
  uint4 u1 = *(const uint4*)(row + lane * 16 + 8);
  unsigned uu[8] = {u0.x, u0.y, u0.z, u0.w, u1.x, u1.y, u1.z, u1.w};
  float v[16];
#pragma unroll
  for (int q = 0; q < 8; ++q) {
    v[2*q]   = __uint_as_float(uu[q] << 16);
    v[2*q+1] = __uint_as_float(uu[q] & 0xffff0000u);
  }
  float mx = v[0];
#pragma unroll
  for (int e = 1; e < 16; ++e) mx = fmaxf(mx, v[e]);
#pragma unroll
  for (int off = 32; off >= 1; off >>= 1) mx = fmaxf(mx, __shfl_xor(mx, off));
  float s = 0.f;
#pragma unroll
  for (int e = 0; e < 16; ++e) s += __expf(v[e] - mx);
#pragma unroll
  for (int off = 32; off >= 1; off >>= 1) s += __shfl_xor(s, off);
  float lse = __logf(s) + mx;
  unsigned short* xr = Xg + (size_t)p * 4096;
#pragma unroll
  for (int e = 0; e < 16; ++e) xr[(lane * 16 + e) * 4 + g] = f2bf(v[e] - lse + LSM_SHIFT);
}

// Recurrent layer, one block per batch element, weights REGISTER-RESIDENT.
// 512 threads = (kg 0..1) x (jg 0..255). Thread (kg,jg) owns, for each gate
// i in {r,z,n}, the K-half [128kg,128kg+128) of row i*256+jg as 16 uint4 of
// packed bf16 pairs (192 VGPRs), preloaded once. Per step: 16 ds_read_b128
// of packed h + 192 v_dot2, 2-way partial reduce in LDS, gate math on
// tid<256, h repacked to LDS. gi prefetched one step ahead.
// L==0: writes h bf16 rows (K-major, feeds gi1 GEMM). L==1: fp32 out.
template <int L>
__global__ __launch_bounds__(512, 2) void k_rnn(const float* __restrict__ gi,
    const unsigned* __restrict__ Wp, const float* __restrict__ bhh,
    unsigned short* __restrict__ hb_out, float* __restrict__ hf_out,
    float* __restrict__ hn_row) {
  const int b = blockIdx.x, tid = threadIdx.x;
  const int jg = tid & 255, kg = tid >> 8;
  __shared__ __align__(16) unsigned hpk[128];
  __shared__ float part[2][776];

  // ---- preload weights into registers (48 x uint4 = 192 VGPRs) ----
  uint4 w[3][16];
#pragma unroll
  for (int i = 0; i < 3; ++i)
#pragma unroll
    for (int c = 0; c < 16; ++c)
      w[i][c] = *(const uint4*)(Wp + ((((i * 2 + kg) * 16 + c) << 10) + (jg << 2)));

  float hprev = 0.f;
  float br = 0.f, bz = 0.f, bn = 0.f;
  float g0 = 0.f, g1 = 0.f, g2 = 0.f;
  if (tid < 256) {
    br = bhh[jg]; bz = bhh[256 + jg]; bn = bhh[512 + jg];
    const float* gr = gi + (size_t)(0 * BAT + b) * 768;
    g0 = gr[jg]; g1 = gr[256 + jg]; g2 = gr[512 + jg];
  }
  if (tid < 128) hpk[tid] = 0u;
  __syncthreads();

  for (int t = 0; t < SEQL; ++t) {
    // prefetch gi for t+1 (full dot-phase of slack hides latency)
    float p0 = 0.f, p1 = 0.f, p2 = 0.f;
    if (tid < 256) {
      int tt = t + 1 < SEQL ? t + 1 : SEQL - 1;
      const float* gr = gi + (size_t)(tt * BAT + b) * 768;
      p0 = gr[jg]; p1 = gr[256 + jg]; p2 = gr[512 + jg];
    }
    // ---- dot phase: h from LDS, weights from registers ----
    float a0 = 0.f, a1 = 0.f, a2 = 0.f;
#pragma unroll
    for (int c = 0; c < 16; ++c) {
      uint4 hk = *(const uint4*)&hpk[kg * 64 + c * 4];
      a0 = dot2bf(w[0][c].x, hk.x, a0); a0 = dot2bf(w[0][c].y, hk.y, a0);
      a0 = dot2bf(w[0][c].z, hk.z, a0); a0 = dot2bf(w[0][c].w, hk.w, a0);
      a1 = dot2bf(w[1][c].x, hk.x, a1); a1 = dot2bf(w[1][c].y, hk.y, a1);
      a1 = dot2bf(w[1][c].z, hk.z, a1); a1 = dot2bf(w[1][c].w, hk.w, a1);
      a2 = dot2bf(w[2][c].x, hk.x, a2); a2 = dot2bf(w[2][c].y, hk.y, a2);
      a2 = dot2bf(w[2][c].z, hk.z, a2); a2 = dot2bf(w[2][c].w, hk.w, a2);
    }
    part[kg][jg]       = a0;
    part[kg][256 + jg] = a1;
    part[kg][512 + jg] = a2;
    __syncthreads();
    // ---- gate phase ----
    if (tid < 256) {
      float ghr = part[0][jg]       + part[1][jg]       + br;
      float ghz = part[0][256 + jg] + part[1][256 + jg] + bz;
      float ghn = part[0][512 + jg] + part[1][512 + jg] + bn;
      float r = sigm(g0 + ghr);
      float z = sigm(g1 + ghz);
      float nn = tanhf(g2 + r * ghn);
      float hnew = (1.f - z) * nn + z * hprev;
      hprev = hnew;
      unsigned short hbb = f2bf(hnew);
      if (L == 0) hb_out[(size_t)(t * BAT + b) * 256 + jg] = hbb;
      else        hf_out[(size_t)(t * BAT + b) * 256 + jg] = hnew;
      unsigned lo = (unsigned)hbb;
      unsigned hi = (unsigned)__shfl_down((int)lo, 1);
      if (!(jg & 1)) hpk[jg >> 1] = lo | (hi << 16);
      if (t == SEQL - 1) hn_row[b * 256 + jg] = hnew;
    }
    g0 = p0; g1 = p1; g2 = p2;
    __syncthreads();
  }
}

extern "C" void kernel_launch(void* const* d_in, const int* in_sizes, int n_in,
                              void* d_out, int out_size, void* d_ws, size_t ws_size,
                              hipStream_t stream) {
  const float* x    = (const float*)d_in[0];
  const float* adj  = (const float*)d_in[1];
  const float* gc1w = (const float*)d_in[2];
  const float* gc1b = (const float*)d_in[3];
  const float* gc2w = (const float*)d_in[4];
  const float* gc2b = (const float*)d_in[5];
  const float* wih0 = (const float*)d_in[6];
  const float* whh0 = (const float*)d_in[7];
  const float* bih0 = (const float*)d_in[8];
  const float* bhh0 = (const float*)d_in[9];
  const float* wih1 = (const float*)d_in[10];
  const float* whh1 = (const float*)d_in[11];
  const float* bih1 = (const float*)d_in[12];
  const float* bhh1 = (const float*)d_in[13];

  char* ws = (char*)d_ws;
  const size_t MB = 1048576;
  unsigned short* adjb  = (unsigned short*)(ws + 0);
  unsigned short* Yt    = (unsigned short*)(ws + 2 * MB);
  unsigned short* z1t   = (unsigned short*)(ws + 18 * MB);
  unsigned short* Y2t   = (unsigned short*)(ws + 34 * MB);
  unsigned short* z2t   = (unsigned short*)(ws + 2 * MB);
  unsigned short* Xg    = (unsigned short*)(ws + 34 * MB);
  unsigned short* wih0b = (unsigned short*)(ws + 2 * MB);
  float* biasAdj        = (float*)(ws + 9 * MB);
  float* gi0            = (float*)(ws + 10 * MB);
  unsigned* Whh0p       = (unsigned*)(ws + 23 * MB);
  unsigned* Whh1p       = (unsigned*)(ws + 24 * MB);
  unsigned short* wih1b = (unsigned short*)(ws + 25 * MB);
  unsigned short* h0b   = (unsigned short*)(ws + 25 * MB + 512 * 1024);
  float* gi1            = (float*)(ws + 28 * MB);
  float* out = (float*)d_out;
  float* hn  = out + (size_t)SEQL * BAT * HH;

  // GCN stage
  k1_xw1<<<PQ * NN / 256, 256, 0, stream>>>(x, gc1w, gc1b, Yt);
  k_cvt<<<(NN * NN / 4 + 255) / 256, 256, 0, stream>>>(adj, adjb, NN * NN / 4);
  gemm_bt<0><<<dim3(64, 8), 256, 0, stream>>>(adjb, Yt, (void*)z1t, nullptr, 1024, 1024);
  k4_w2<<<16384 * 128 / 256, 256, 0, stream>>>(z1t, gc2w, gc2b, Y2t);
  gemm_bt<1><<<dim3(128, 8), 256, 0, stream>>>(adjb, Y2t, (void*)z2t, nullptr, 1024, 1024);
  k6_lsm<<<16384 / 4, 256, 0, stream>>>(z2t, Xg);
  // GRU layer-0 input GEMM (all timesteps), exact fp32 shift-correction bias
  k_biasadj<<<192, 256, 0, stream>>>(wih0, bih0, biasAdj);
  k_cvt<<<(768 * 4096 / 4 + 255) / 256, 256, 0, stream>>>(wih0, wih0b, 768 * 4096 / 4);
  gemm_bt<2><<<dim3(6, 32), 256, 0, stream>>>(Xg, wih0b, (void*)gi0, biasAdj, 4096, 768);
  // Recurrence weight prep
  k_prep<<<384, 256, 0, stream>>>(whh0, Whh0p);
  k_prep<<<384, 256, 0, stream>>>(whh1, Whh1p);
  k_cvt<<<(768 * 256 / 4 + 255) / 256, 256, 0, stream>>>(wih1, wih1b, 768 * 256 / 4);
  // Layer 0 recurrence (32 independent chains, weights in VGPRs)
  k_rnn<0><<<32, 512, 0, stream>>>(gi0, Whh0p, bhh0, h0b, nullptr, hn);
  // Layer 1 input GEMM: gi1 = H0 @ wih1^T + bih1
  gemm_bt<2><<<dim3(6, 32), 256, 0, stream>>>(h0b, wih1b, (void*)gi1, bih1, 256, 768);
  // Layer 1 recurrence -> writes final out + hn[1]
  k_rnn<1><<<32, 512, 0, stream>>>(gi1, Whh1p, bhh1, nullptr, out, hn + BAT * HH);
}

// Round 5
// 655.548 us; speedup vs baseline: 7.5511x; 1.0063x over previous
//
#include <hip/hip_runtime.h>
#include <stdint.h>

constexpr int SEQL = 128;
constexpr int BAT  = 32;
constexpr int NN   = 1024;   // nodes
constexpr int FIN  = 16;
constexpr int HH   = 256;    // GRU hidden
constexpr int PQ   = SEQL * BAT;   // 4096 (seq*batch pairs)
constexpr float LSM_SHIFT = 6.9314718055994531f;  // ln(1024)

using f32x4 = __attribute__((ext_vector_type(4))) float;
using s16x8 = __attribute__((ext_vector_type(8))) short;
using u32x4 = __attribute__((ext_vector_type(4))) unsigned int;

__device__ __forceinline__ unsigned short f2bf(float x) {
  unsigned u = __float_as_uint(x);
  u += 0x7fffu + ((u >> 16) & 1u);
  return (unsigned short)(u >> 16);
}
__device__ __forceinline__ float sigm(float x) { return 1.f / (1.f + __expf(-x)); }

__device__ __forceinline__ void gl_lds16(const void* g, void* l) {
  __builtin_amdgcn_global_load_lds(
      (const __attribute__((address_space(1))) void*)g,
      (__attribute__((address_space(3))) void*)l, 16, 0, 0);
}

// packed bf16-pair dot product: acc += w.lo*h.lo + w.hi*h.hi
#if __has_builtin(__builtin_amdgcn_fdot2_f32_bf16)
typedef __bf16 bf16x2_t __attribute__((ext_vector_type(2)));
__device__ __forceinline__ float dot2bf(unsigned w, unsigned h, float acc) {
  return __builtin_amdgcn_fdot2_f32_bf16(__builtin_bit_cast(bf16x2_t, w),
                                         __builtin_bit_cast(bf16x2_t, h), acc, false);
}
#else
__device__ __forceinline__ float dot2bf(unsigned w, unsigned h, float acc) {
  acc += __uint_as_float(w << 16) * __uint_as_float(h << 16);
  acc += __uint_as_float(w & 0xffff0000u) * __uint_as_float(h & 0xffff0000u);
  return acc;
}
#endif

// K1: y = x @ gc1_w + gc1_b, written transposed: Yt[(p*2+h)][n], bf16
__global__ __launch_bounds__(256) void k1_xw1(const float* __restrict__ x,
    const float* __restrict__ w1, const float* __restrict__ b1,
    unsigned short* __restrict__ Yt) {
  int idx = blockIdx.x * 256 + threadIdx.x;   // = p*1024 + n
  int p = idx >> 10, n = idx & 1023;
  const float* xp = x + (size_t)idx * FIN;
  float xv[16];
  *(float4*)(xv + 0)  = *(const float4*)(xp + 0);
  *(float4*)(xv + 4)  = *(const float4*)(xp + 4);
  *(float4*)(xv + 8)  = *(const float4*)(xp + 8);
  *(float4*)(xv + 12) = *(const float4*)(xp + 12);
  float y0 = b1[0], y1 = b1[1];
#pragma unroll
  for (int f = 0; f < 16; ++f) { y0 += xv[f] * w1[2*f]; y1 += xv[f] * w1[2*f+1]; }
  Yt[(size_t)(2*p)   * NN + n] = f2bf(y0);
  Yt[(size_t)(2*p+1) * NN + n] = f2bf(y1);
}

// generic fp32 -> bf16 conversion (4 elements / thread)
__global__ __launch_bounds__(256) void k_cvt(const float* __restrict__ in,
    unsigned short* __restrict__ out, int n4) {
  int i = blockIdx.x * 256 + threadIdx.x;
  if (i >= n4) return;
  float4 v = *(const float4*)(in + (size_t)i * 4);
  ushort4 o;
  o.x = f2bf(v.x); o.y = f2bf(v.y); o.z = f2bf(v.z); o.w = f2bf(v.w);
  *(ushort4*)(out + (size_t)i * 4) = o;
}

// biasAdj[j] = bih0[j] - C * sum_k wih0[j][k]   (fp32, one wave per row)
__global__ __launch_bounds__(256) void k_biasadj(const float* __restrict__ wih0,
    const float* __restrict__ bih0, float* __restrict__ biasAdj) {
  int wid = threadIdx.x >> 6, lane = threadIdx.x & 63;
  int j = blockIdx.x * 4 + wid;
  const float* row = wih0 + (size_t)j * 4096;
  float s = 0.f;
  for (int k = lane * 4; k < 4096; k += 256) {
    float4 v = *(const float4*)(row + k);
    s += v.x + v.y + v.z + v.w;
  }
#pragma unroll
  for (int off = 32; off >= 1; off >>= 1) s += __shfl_xor(s, off);
  if (lane == 0) biasAdj[j] = bih0[j] - LSM_SHIFT * s;
}

// Weight prep for the register-resident recurrence.
// W fp32 [768][256] -> packed k-pair bf16 uints in gather layout:
// element (j,k2): i=j>>8, jg=j&255, kg=k2>>6, c=(k2>>2)&15, u=k2&3
//   -> Wp[(((i*2+kg)*16+c)<<10) + (jg<<2) + u]
__global__ __launch_bounds__(256) void k_prep(const float* __restrict__ W,
    unsigned* __restrict__ Wp) {
  int tid = blockIdx.x * 256 + threadIdx.x;  // 98304
  int j = tid >> 7, k2 = tid & 127;
  float2 wv = *(const float2*)(W + (size_t)j * 256 + 2 * k2);
  unsigned pk = (unsigned)f2bf(wv.x) | ((unsigned)f2bf(wv.y) << 16);
  int i = j >> 8, jg = j & 255, kg = k2 >> 6, c = (k2 >> 2) & 15, u = k2 & 3;
  Wp[(((i * 2 + kg) * 16 + c) << 10) + (jg << 2) + u] = pk;
}

// MFMA GEMM: C[m][j] = sum_k A[m][k]*B[j][k]; A:(M x K) K-major, B:(N x K) K-major.
// EPI 0: write bf16 transposed C[j][m] with relu; EPI 1: same, no relu;
// EPI 2: write fp32 C[m][j] with per-column bias.
template <int EPI>
__global__ __launch_bounds__(256) void gemm_bt(
    const unsigned short* __restrict__ A, const unsigned short* __restrict__ B,
    void* __restrict__ Cout, const float* __restrict__ bias, int K, int ldc) {
  __shared__ __align__(16) unsigned short As[128 * 64];
  __shared__ __align__(16) unsigned short Bs[128 * 64];
  const int tid = threadIdx.x;
  const int lane = tid & 63, wave = tid >> 6;
  const int ln15 = lane & 15, hi4 = lane >> 4;
  const int wr = wave >> 1, wc = wave & 1;
  const int m0 = blockIdx.y * 128, n0 = blockIdx.x * 128;
  const int rsub = lane >> 3, csub = lane & 7;

  f32x4 acc[4][4];
#pragma unroll
  for (int i = 0; i < 4; ++i)
#pragma unroll
    for (int j = 0; j < 4; ++j) acc[i][j] = {0.f, 0.f, 0.f, 0.f};

  for (int kt = 0; kt < K; kt += 64) {
    __syncthreads();
#pragma unroll
    for (int j = 0; j < 4; ++j) {
      int qq = wave * 4 + j;
      const unsigned short* ga = A + (size_t)(m0 + qq*8 + rsub) * K + kt + csub*8;
      gl_lds16(ga, &As[qq * 512]);
      const unsigned short* gb = B + (size_t)(n0 + qq*8 + rsub) * K + kt + csub*8;
      gl_lds16(gb, &Bs[qq * 512]);
    }
    __syncthreads();
#pragma unroll
    for (int kk = 0; kk < 2; ++kk) {
      s16x8 af[4], bfr[4];
#pragma unroll
      for (int mi = 0; mi < 4; ++mi)
        af[mi] = *(const s16x8*)&As[(wr*64 + mi*16 + ln15) * 64 + kk*32 + hi4*8];
#pragma unroll
      for (int ni = 0; ni < 4; ++ni)
        bfr[ni] = *(const s16x8*)&Bs[(wc*64 + ni*16 + ln15) * 64 + kk*32 + hi4*8];
#pragma unroll
      for (int mi = 0; mi < 4; ++mi)
#pragma unroll
        for (int ni = 0; ni < 4; ++ni)
          acc[mi][ni] = __builtin_amdgcn_mfma_f32_16x16x32_bf16(
              af[mi], bfr[ni], acc[mi][ni], 0, 0, 0);
    }
  }

  if (EPI == 2) {
    float* C = (float*)Cout;
#pragma unroll
    for (int ni = 0; ni < 4; ++ni) {
      int j = n0 + wc*64 + ni*16 + ln15;
      float bv = bias[j];
#pragma unroll
      for (int mi = 0; mi < 4; ++mi) {
        int m = m0 + wr*64 + mi*16 + hi4*4;
#pragma unroll
        for (int r = 0; r < 4; ++r) C[(size_t)(m + r) * ldc + j] = acc[mi][ni][r] + bv;
      }
    }
  } else {
    unsigned short* C = (unsigned short*)Cout;
#pragma unroll
    for (int ni = 0; ni < 4; ++ni) {
      int j = n0 + wc*64 + ni*16 + ln15;
#pragma unroll
      for (int mi = 0; mi < 4; ++mi) {
        int m = m0 + wr*64 + mi*16 + hi4*4;
        ushort4 v;
        float f0 = acc[mi][ni][0], f1 = acc[mi][ni][1], f2 = acc[mi][ni][2], f3 = acc[mi][ni][3];
        if (EPI == 0) { f0 = fmaxf(f0, 0.f); f1 = fmaxf(f1, 0.f); f2 = fmaxf(f2, 0.f); f3 = fmaxf(f3, 0.f); }
        v.x = f2bf(f0); v.y = f2bf(f1); v.z = f2bf(f2); v.w = f2bf(f3);
        *(ushort4*)&C[(size_t)j * ldc + m] = v;
      }
    }
  }
}

__device__ __forceinline__ unsigned k4_proc(unsigned a, unsigned b, float w0, float w1, float bb) {
  float a0 = __uint_as_float(a << 16), a1 = __uint_as_float(a & 0xffff0000u);
  float b0 = __uint_as_float(b << 16), b1 = __uint_as_float(b & 0xffff0000u);
  float y0 = a0 * w0 + b0 * w1 + bb;
  float y1 = a1 * w0 + b1 * w1 + bb;
  return (unsigned)f2bf(y0) | ((unsigned)f2bf(y1) << 16);
}

// K4: Y2t[(p*4+g)][m] = z1t[(p*2+0)][m]*W2[0][g] + z1t[(p*2+1)][m]*W2[1][g] + b2[g]
__global__ __launch_bounds__(256) void k4_w2(const unsigned short* __restrict__ z1t,
    const float* __restrict__ w2, const float* __restrict__ b2,
    unsigned short* __restrict__ Y2t) {
  int idx = blockIdx.x * 256 + threadIdx.x;
  int j4 = idx >> 7, mb = idx & 127;
  int p = j4 >> 2, g = j4 & 3;
  const unsigned short* r0 = z1t + (size_t)(p * 2) * NN + mb * 8;
  const unsigned short* r1 = r0 + NN;
  float w0 = w2[g], w1v = w2[4 + g], bb = b2[g];
  uint4 ua = *(const uint4*)r0;
  uint4 ub = *(const uint4*)r1;
  uint4 o;
  o.x = k4_proc(ua.x, ub.x, w0, w1v, bb);
  o.y = k4_proc(ua.y, ub.y, w0, w1v, bb);
  o.z = k4_proc(ua.z, ub.z, w0, w1v, bb);
  o.w = k4_proc(ua.w, ub.w, w0, w1v, bb);
  *(uint4*)(Y2t + (size_t)j4 * NN + mb * 8) = o;
}

// K6: log_softmax over node axis, write GRU input Xg[p][m*4+g] bf16,
// shifted by +ln(1024) to keep values near 0 for bf16 precision.
__global__ __launch_bounds__(256) void k6_lsm(const unsigned short* __restrict__ z2t,
    unsigned short* __restrict__ Xg) {
  int wid = threadIdx.x >> 6, lane = threadIdx.x & 63;
  int r = blockIdx.x * 4 + wid;   // row = p*4+g
  int p = r >> 2, g = r & 3;
  const unsigned short* row = z2t + (size_t)r * NN;
  uint4 u0 = *(const uint4*)(row + lane * 16);
  uint4 u1 = *(const uint4*)(row + lane * 16 + 8);
  unsigned uu[8] = {u0.x, u0.y, u0.z, u0.w, u1.x, u1.y, u1.z, u1.w};
  float v[16];
#pragma unroll
  for (int q = 0; q < 8; ++q) {
    v[2*q]   = __uint_as_float(uu[q] << 16);
    v[2*q+1] = __uint_as_float(uu[q] & 0xffff0000u);
  }
  float mx = v[0];
#pragma unroll
  for (int e = 1; e < 16; ++e) mx = fmaxf(mx, v[e]);
#pragma unroll
  for (int off = 32; off >= 1; off >>= 1) mx = fmaxf(mx, __shfl_xor(mx, off));
  float s = 0.f;
#pragma unroll
  for (int e = 0; e < 16; ++e) s += __expf(v[e] - mx);
#pragma unroll
  for (int off = 32; off >= 1; off >>= 1) s += __shfl_xor(s, off);
  float lse = __logf(s) + mx;
  unsigned short* xr = Xg + (size_t)p * 4096;
#pragma unroll
  for (int e = 0; e < 16; ++e) xr[(lane * 16 + e) * 4 + g] = f2bf(v[e] - lse + LSM_SHIFT);
}

// Recurrent layer, one block per batch element, weights REGISTER-RESIDENT.
// 512 threads = (kg 0..1) x (jg 0..255). Thread (kg,jg) owns, for each gate
// i in {r,z,n}, the K-half [128kg,128kg+128) of row i*256+jg as 64 packed
// bf16-pair uints (192 VGPRs), preloaded once and PINNED into architectural
// VGPRs via opaque asm (prevents AGPR placement / load sinking).
// __launch_bounds__(512,1): 512-VGPR budget; occupancy is block-limited at
// 8 waves/CU regardless, so nothing is lost.
template <int L>
__global__ __launch_bounds__(512, 1) void k_rnn(const float* __restrict__ gi,
    const unsigned* __restrict__ Wp, const float* __restrict__ bhh,
    unsigned short* __restrict__ hb_out, float* __restrict__ hf_out,
    float* __restrict__ hn_row) {
  const int b = blockIdx.x, tid = threadIdx.x;
  const int jg = tid & 255, kg = tid >> 8;
  __shared__ __align__(16) unsigned hpk[128];
  __shared__ float part[2][776];

  // ---- preload weights into registers (192 scalar VGPRs) ----
  unsigned w[3][16][4];
#pragma unroll
  for (int i = 0; i < 3; ++i)
#pragma unroll
    for (int c = 0; c < 16; ++c) {
      u32x4 t = *(const u32x4*)(Wp + ((((i * 2 + kg) * 16 + c) << 10) + (jg << 2)));
      w[i][c][0] = t.x; w[i][c][1] = t.y; w[i][c][2] = t.z; w[i][c][3] = t.w;
    }
  // pin: opaque write makes loads non-rematerializable and forces arch VGPRs
#pragma unroll
  for (int i = 0; i < 3; ++i)
#pragma unroll
    for (int c = 0; c < 16; ++c)
#pragma unroll
      for (int u = 0; u < 4; ++u)
        asm volatile("" : "+v"(w[i][c][u]));

  float hprev = 0.f;
  float br = 0.f, bz = 0.f, bn = 0.f;
  float g0 = 0.f, g1 = 0.f, g2 = 0.f;
  if (tid < 256) {
    br = bhh[jg]; bz = bhh[256 + jg]; bn = bhh[512 + jg];
    const float* gr = gi + (size_t)(0 * BAT + b) * 768;
    g0 = gr[jg]; g1 = gr[256 + jg]; g2 = gr[512 + jg];
  }
  if (tid < 128) hpk[tid] = 0u;
  __syncthreads();

  for (int t = 0; t < SEQL; ++t) {
    // prefetch gi for t+1 (full dot-phase of slack hides latency)
    float p0 = 0.f, p1 = 0.f, p2 = 0.f;
    if (tid < 256) {
      int tt = t + 1 < SEQL ? t + 1 : SEQL - 1;
      const float* gr = gi + (size_t)(tt * BAT + b) * 768;
      p0 = gr[jg]; p1 = gr[256 + jg]; p2 = gr[512 + jg];
    }
    // ---- dot phase: h from LDS (uniform-address broadcast), w from VGPRs ----
    float a0 = 0.f, a1 = 0.f, a2 = 0.f;
#pragma unroll
    for (int c = 0; c < 16; ++c) {
      u32x4 hk = *(const u32x4*)&hpk[kg * 64 + c * 4];
      a0 = dot2bf(w[0][c][0], hk.x, a0); a0 = dot2bf(w[0][c][1], hk.y, a0);
      a0 = dot2bf(w[0][c][2], hk.z, a0); a0 = dot2bf(w[0][c][3], hk.w, a0);
      a1 = dot2bf(w[1][c][0], hk.x, a1); a1 = dot2bf(w[1][c][1], hk.y, a1);
      a1 = dot2bf(w[1][c][2], hk.z, a1); a1 = dot2bf(w[1][c][3], hk.w, a1);
      a2 = dot2bf(w[2][c][0], hk.x, a2); a2 = dot2bf(w[2][c][1], hk.y, a2);
      a2 = dot2bf(w[2][c][2], hk.z, a2); a2 = dot2bf(w[2][c][3], hk.w, a2);
    }
    part[kg][jg]       = a0;
    part[kg][256 + jg] = a1;
    part[kg][512 + jg] = a2;
    __syncthreads();
    // ---- gate phase ----
    if (tid < 256) {
      float ghr = part[0][jg]       + part[1][jg]       + br;
      float ghz = part[0][256 + jg] + part[1][256 + jg] + bz;
      float ghn = part[0][512 + jg] + part[1][512 + jg] + bn;
      float r = sigm(g0 + ghr);
      float z = sigm(g1 + ghz);
      float nn = tanhf(g2 + r * ghn);
      float hnew = (1.f - z) * nn + z * hprev;
      hprev = hnew;
      unsigned short hbb = f2bf(hnew);
      if (L == 0) hb_out[(size_t)(t * BAT + b) * 256 + jg] = hbb;
      else        hf_out[(size_t)(t * BAT + b) * 256 + jg] = hnew;
      unsigned lo = (unsigned)hbb;
      unsigned hi = (unsigned)__shfl_down((int)lo, 1);
      if (!(jg & 1)) hpk[jg >> 1] = lo | (hi << 16);
      if (t == SEQL - 1) hn_row[b * 256 + jg] = hnew;
    }
    g0 = p0; g1 = p1; g2 = p2;
    __syncthreads();
  }
}

extern "C" void kernel_launch(void* const* d_in, const int* in_sizes, int n_in,
                              void* d_out, int out_size, void* d_ws, size_t ws_size,
                              hipStream_t stream) {
  const float* x    = (const float*)d_in[0];
  const float* adj  = (const float*)d_in[1];
  const float* gc1w = (const float*)d_in[2];
  const float* gc1b = (const float*)d_in[3];
  const float* gc2w = (const float*)d_in[4];
  const float* gc2b = (const float*)d_in[5];
  const float* wih0 = (const float*)d_in[6];
  const float* whh0 = (const float*)d_in[7];
  const float* bih0 = (const float*)d_in[8];
  const float* bhh0 = (const float*)d_in[9];
  const float* wih1 = (const float*)d_in[10];
  const float* whh1 = (const float*)d_in[11];
  const float* bih1 = (const float*)d_in[12];
  const float* bhh1 = (const float*)d_in[13];

  char* ws = (char*)d_ws;
  const size_t MB = 1048576;
  unsigned short* adjb  = (unsigned short*)(ws + 0);
  unsigned short* Yt    = (unsigned short*)(ws + 2 * MB);
  unsigned short* z1t   = (unsigned short*)(ws + 18 * MB);
  unsigned short* Y2t   = (unsigned short*)(ws + 34 * MB);
  unsigned short* z2t   = (unsigned short*)(ws + 2 * MB);
  unsigned short* Xg    = (unsigned short*)(ws + 34 * MB);
  unsigned short* wih0b = (unsigned short*)(ws + 2 * MB);
  float* biasAdj        = (float*)(ws + 9 * MB);
  float* gi0            = (float*)(ws + 10 * MB);
  unsigned* Whh0p       = (unsigned*)(ws + 23 * MB);
  unsigned* Whh1p       = (unsigned*)(ws + 24 * MB);
  unsigned short* wih1b = (unsigned short*)(ws + 25 * MB);
  unsigned short* h0b   = (unsigned short*)(ws + 25 * MB + 512 * 1024);
  float* gi1            = (float*)(ws + 28 * MB);
  float* out = (float*)d_out;
  float* hn  = out + (size_t)SEQL * BAT * HH;

  // GCN stage
  k1_xw1<<<PQ * NN / 256, 256, 0, stream>>>(x, gc1w, gc1b, Yt);
  k_cvt<<<(NN * NN / 4 + 255) / 256, 256, 0, stream>>>(adj, adjb, NN * NN / 4);
  gemm_bt<0><<<dim3(64, 8), 256, 0, stream>>>(adjb, Yt, (void*)z1t, nullptr, 1024, 1024);
  k4_w2<<<16384 * 128 / 256, 256, 0, stream>>>(z1t, gc2w, gc2b, Y2t);
  gemm_bt<1><<<dim3(128, 8), 256, 0, stream>>>(adjb, Y2t, (void*)z2t, nullptr, 1024, 1024);
  k6_lsm<<<16384 / 4, 256, 0, stream>>>(z2t, Xg);
  // GRU layer-0 input GEMM (all timesteps), exact fp32 shift-correction bias
  k_biasadj<<<192, 256, 0, stream>>>(wih0, bih0, biasAdj);
  k_cvt<<<(768 * 4096 / 4 + 255) / 256, 256, 0, stream>>>(wih0, wih0b, 768 * 4096 / 4);
  gemm_bt<2><<<dim3(6, 32), 256, 0, stream>>>(Xg, wih0b, (void*)gi0, biasAdj, 4096, 768);
  // Recurrence weight prep
  k_prep<<<384, 256, 0, stream>>>(whh0, Whh0p);
  k_prep<<<384, 256, 0, stream>>>(whh1, Whh1p);
  k_cvt<<<(768 * 256 / 4 + 255) / 256, 256, 0, stream>>>(wih1, wih1b, 768 * 256 / 4);
  // Layer 0 recurrence (32 independent chains, weights in VGPRs)
  k_rnn<0><<<32, 512, 0, stream>>>(gi0, Whh0p, bhh0, h0b, nullptr, hn);
  // Layer 1 input GEMM: gi1 = H0 @ wih1^T + bih1
  gemm_bt<2><<<dim3(6, 32), 256, 0, stream>>>(h0b, wih1b, (void*)gi1, bih1, 256, 768);
  // Layer 1 recurrence -> writes final out + hn[1]
  k_rnn<1><<<32, 512, 0, stream>>>(gi1, Whh1p, bhh1, nullptr, out, hn + BAT * HH);
}